// Round 1
// baseline (16128.851 us; speedup 1.0000x reference)
//
#include <hip/hip_runtime.h>
#include <math.h>

#define B    128
#define T    20
#define TD   19      // Tdec
#define V    10000
#define D    1024
#define E    1024
#define A_DIM 1024
#define F    2048
#define NR   36

__device__ __forceinline__ float sigm(float x) { return 1.f / (1.f + __expf(-x)); }

// ---------------------------------------------------------------------------
// Sort (stable descending by sizes), seqs/order outputs, active counts, rowmap
// ---------------------------------------------------------------------------
__global__ void k_sort_init(const int* __restrict__ sizes,
                            const int* __restrict__ sequences,
                            int* __restrict__ order,
                            int* __restrict__ dec_len,
                            int* __restrict__ active,
                            int* __restrict__ seqs_s,
                            int* __restrict__ rowmap,
                            float* __restrict__ out)
{
    int tid = threadIdx.x;                // 128 threads
    __shared__ int s_sizes[B];
    __shared__ int s_dl[B];
    s_sizes[tid] = sizes[tid];
    __syncthreads();
    int si = s_sizes[tid];
    int rank = 0;
    for (int j = 0; j < B; ++j) {
        int sj = s_sizes[j];
        if (sj > si || (sj == si && j < tid)) rank++;
    }
    order[rank] = tid;
    __syncthreads();
    int ob = order[tid];
    int dl = s_sizes[ob] - 1;
    dec_len[tid] = dl;
    s_dl[tid] = dl;
    for (int tt = 0; tt < T; ++tt) {
        int sq = sequences[ob * T + tt];
        seqs_s[tid * T + tt] = sq;
        out[(size_t)B * TD * V + tid * T + tt] = (float)sq;
    }
    out[(size_t)B * TD * V + B * T + tid] = (float)ob;
    __syncthreads();
    if (tid < TD) {
        int c = 0;
        for (int b = 0; b < B; ++b) c += (s_dl[b] > tid) ? 1 : 0;
        active[tid] = c;
    }
    for (int m = tid; m < B * NR; m += B)
        rowmap[m] = order[m / NR] * NR + (m % NR);
    if (tid == 0) out[(size_t)B * TD * V + B * T + B] = 0.f;   // loss accumulator
}

__global__ void k_zero(float* __restrict__ p, int n) {
    int i = blockIdx.x * 256 + threadIdx.x;
    if (i < n) p[i] = 0.f;
}

__global__ void k_copy(const float* __restrict__ s, float* __restrict__ d, int n) {
    int i = blockIdx.x * 256 + threadIdx.x;
    if (i < n) d[i] = s[i];
}

// featsAvg[b][f] = mean_r feats[order[b]][r][f]
__global__ void k_feats_avg(const float* __restrict__ feats, const int* __restrict__ order,
                            float* __restrict__ favg)
{
    int f = blockIdx.x * 256 + threadIdx.x;   // grid.x = 8
    int b = blockIdx.y;
    int ob = order[b];
    const float* base = feats + (size_t)ob * NR * F + f;
    float s = 0.f;
    for (int r = 0; r < NR; ++r) s += base[(size_t)r * F];
    favg[b * F + f] = s * (1.f / NR);
}

// embs_s[b][t][e] = emb[seqs_s[b][t]][e], t < TD
__global__ void k_emb_gather(const float* __restrict__ emb, const int* __restrict__ seqs_s,
                             float* __restrict__ embs_s)
{
    int j = blockIdx.x * 256 + threadIdx.x;   // 0..TD*E-1, grid.x = 76
    int b = blockIdx.y;
    int t = j >> 10, e = j & 1023;
    embs_s[((size_t)b * TD + t) * E + e] = emb[(size_t)seqs_s[b * T + t] * E + e];
}

// concat builders
__global__ void k_concat_td(const float* __restrict__ h2, const float* __restrict__ favg,
                            const float* __restrict__ embs_s, const float* __restrict__ h1,
                            float* __restrict__ xtd, int t)
{
    int k = blockIdx.x * 256 + threadIdx.x;   // grid.x = 20
    int b = blockIdx.y;
    float v;
    if (k < 1024)      v = h2[b * 1024 + k];
    else if (k < 3072) v = favg[b * 2048 + (k - 1024)];
    else if (k < 4096) v = embs_s[((size_t)b * TD + t) * 1024 + (k - 3072)];
    else               v = h1[b * 1024 + (k - 4096)];
    xtd[(size_t)b * 5120 + k] = v;
}

__global__ void k_concat_lg(const float* __restrict__ awe, const float* __restrict__ h1,
                            const float* __restrict__ h2, float* __restrict__ xlg)
{
    int k = blockIdx.x * 256 + threadIdx.x;   // grid.x = 16
    int b = blockIdx.y;
    float v;
    if (k < 2048)      v = awe[b * 2048 + k];
    else if (k < 3072) v = h1[b * 1024 + (k - 2048)];
    else               v = h2[b * 1024 + (k - 3072)];
    xlg[(size_t)b * 4096 + k] = v;
}

__global__ void k_concat_ar(const float* __restrict__ h1, const float* __restrict__ arh,
                            float* __restrict__ xar)
{
    int k = blockIdx.x * 256 + threadIdx.x;   // grid.x = 8
    int b = blockIdx.y;
    xar[(size_t)b * 2048 + k] = (k < 1024) ? h1[b * 1024 + k] : arh[b * 1024 + (k - 1024)];
}

// ---------------------------------------------------------------------------
// Generic GEMM: C[m][n] = sum_k A[m][k] * W[n][k]  (+bias (+bias2))
//   W split in two row-major chunks along K:  [W1 (K1) | W2 (Ktot-K1)]
//   modes: 0 = plain store; 1 = store (v - sub[m*1024+n]); 2 = zero rows >= *actp
//   Tile 64x32, BK=16, 256 threads, each thread 4x2.
// ---------------------------------------------------------------------------
#define GBM 64
#define GBN 32
#define GBK 16

__global__ __launch_bounds__(256)
void k_gemm(const float* __restrict__ Amat, const int* __restrict__ rowmap,
            const float* __restrict__ W1, int K1,
            const float* __restrict__ W2, int Ktot,
            const float* __restrict__ bias, const float* __restrict__ bias2,
            float* __restrict__ C, int ldc, int N,
            int mode, const float* __restrict__ sub, const int* __restrict__ actp)
{
    __shared__ __align__(16) float As[GBK][GBM + 4];
    __shared__ __align__(16) float Ws[GBK][GBN + 4];
    int tid = threadIdx.x;
    int bm = blockIdx.x * GBM;
    int bn = blockIdx.y * GBN;
    int tx = tid & 15;          // 16 col groups * 2
    int ty = tid >> 4;          // 16 row groups * 4
    int lrA = tid >> 2;         // 0..63
    int lkA = (tid & 3) << 2;   // 0,4,8,12
    int lrW = tid >> 3;         // 0..31
    int lkW = (tid & 7) << 1;   // 0..14 step 2
    int garow = bm + lrA;
    if (rowmap) garow = rowmap[garow];
    const float* aptr = Amat + (size_t)garow * Ktot;
    int wrow = bn + lrW;
    bool wvalid = wrow < N;
    int K2 = Ktot - K1;

    float acc[4][2];
#pragma unroll
    for (int i = 0; i < 4; ++i) { acc[i][0] = 0.f; acc[i][1] = 0.f; }

    for (int k0 = 0; k0 < Ktot; k0 += GBK) {
        float4 av = *(const float4*)(aptr + k0 + lkA);
        float2 wv = make_float2(0.f, 0.f);
        if (wvalid) {
            if (k0 < K1) wv = *(const float2*)(W1 + (size_t)wrow * K1 + k0 + lkW);
            else         wv = *(const float2*)(W2 + (size_t)wrow * K2 + (k0 - K1) + lkW);
        }
        __syncthreads();
        As[lkA + 0][lrA] = av.x; As[lkA + 1][lrA] = av.y;
        As[lkA + 2][lrA] = av.z; As[lkA + 3][lrA] = av.w;
        Ws[lkW + 0][lrW] = wv.x; Ws[lkW + 1][lrW] = wv.y;
        __syncthreads();
#pragma unroll
        for (int kk = 0; kk < GBK; ++kk) {
            float4 a = *(const float4*)&As[kk][ty << 2];
            float2 bv = *(const float2*)&Ws[kk][tx << 1];
            acc[0][0] += a.x * bv.x; acc[0][1] += a.x * bv.y;
            acc[1][0] += a.y * bv.x; acc[1][1] += a.y * bv.y;
            acc[2][0] += a.z * bv.x; acc[2][1] += a.z * bv.y;
            acc[3][0] += a.w * bv.x; acc[3][1] += a.w * bv.y;
        }
    }

    int act = (mode == 2) ? *actp : B;
#pragma unroll
    for (int i = 0; i < 4; ++i) {
        int r = bm + (ty << 2) + i;
#pragma unroll
        for (int j = 0; j < 2; ++j) {
            int c = bn + (tx << 1) + j;
            if (c >= N) continue;
            float v = acc[i][j] + bias[c];
            if (bias2) v += bias2[c];
            if (mode == 1) v -= sub[(size_t)r * 1024 + c];
            if (mode == 2 && r >= act) v = 0.f;
            C[(size_t)r * ldc + c] = v;
        }
    }
}

// LSTM pointwise: gates[b][4096] (i,f,g,o quarters, biases already added) -> h,c
__global__ void k_lstm(const float* __restrict__ gates, float* __restrict__ h,
                       float* __restrict__ c, const int* __restrict__ actp)
{
    int idx = blockIdx.x * 256 + threadIdx.x;   // 131072, grid 512
    int b = idx >> 10;
    if (b >= *actp) return;                     // frozen rows: skip write
    int n = idx & 1023;
    const float* g = gates + (size_t)b * 4096;
    float gi = g[n], gf = g[1024 + n], gg = g[2048 + n], go = g[3072 + n];
    float cc = c[idx];
    float c2 = sigm(gf) * cc + sigm(gi) * tanhf(gg);
    c[idx] = c2;
    h[idx] = sigm(go) * tanhf(c2);
}

// attention: e = relu(h1a + img_att) . aw_w + aw_b ; softmax over 36 ; awe = alpha^T feats
__global__ __launch_bounds__(256)
void k_attn(const float* __restrict__ h1a, const float* __restrict__ img_att,
            const float* __restrict__ aw_w, const float* __restrict__ aw_b,
            const float* __restrict__ feats, const int* __restrict__ order,
            float* __restrict__ awe)
{
    int b = blockIdx.x;
    int tid = threadIdx.x;
    __shared__ float sh[A_DIM];
    __shared__ float se[NR];
    for (int i = tid; i < A_DIM; i += 256) sh[i] = h1a[b * A_DIM + i];
    __syncthreads();
    int wid = tid >> 6, lane = tid & 63;
    for (int r = wid; r < NR; r += 4) {
        const float* row = img_att + ((size_t)b * NR + r) * A_DIM;
        float s = 0.f;
        for (int a = lane; a < A_DIM; a += 64)
            s += fmaxf(sh[a] + row[a], 0.f) * aw_w[a];
        for (int off = 32; off > 0; off >>= 1) s += __shfl_down(s, off, 64);
        if (lane == 0) se[r] = s + aw_b[0];
    }
    __syncthreads();
    if (tid == 0) {
        float m = se[0];
        for (int r = 1; r < NR; ++r) m = fmaxf(m, se[r]);
        float ssum = 0.f;
        for (int r = 0; r < NR; ++r) { float ex = __expf(se[r] - m); se[r] = ex; ssum += ex; }
        float inv = 1.f / ssum;
        for (int r = 0; r < NR; ++r) se[r] *= inv;
    }
    __syncthreads();
    int ob = order[b];
    const float* fb = feats + (size_t)ob * NR * F;
    for (int f = tid; f < F; f += 256) {
        float s = 0.f;
        for (int r = 0; r < NR; ++r) s += se[r] * fb[(size_t)r * F + f];
        awe[b * F + f] = s;
    }
}

// loss += sum_b<act ||diff_b||^2 * 0.005 / act
__global__ void k_loss(const float* __restrict__ diff, const int* __restrict__ actp,
                       float* __restrict__ loss)
{
    int b = blockIdx.x;
    int act = *actp;
    if (b >= act) return;
    int tid = threadIdx.x;
    float s = 0.f;
    for (int d = tid; d < D; d += 256) { float v = diff[b * D + d]; s += v * v; }
    for (int off = 32; off > 0; off >>= 1) s += __shfl_down(s, off, 64);
    __shared__ float ps[4];
    int wid = tid >> 6, lane = tid & 63;
    if (lane == 0) ps[wid] = s;
    __syncthreads();
    if (tid == 0) {
        float tot = ps[0] + ps[1] + ps[2] + ps[3];
        atomicAdd(loss, tot * (0.005f / (float)act));
    }
}

// ---------------------------------------------------------------------------
extern "C" void kernel_launch(void* const* d_in, const int* in_sizes, int n_in,
                              void* d_out, int out_size, void* d_ws, size_t ws_size,
                              hipStream_t stream)
{
    const float* feats     = (const float*)d_in[0];
    const int*   sequences = (const int*)d_in[1];
    const int*   sizes     = (const int*)d_in[2];
    const float* emb       = (const float*)d_in[3];
    const float* td_wi = (const float*)d_in[4];
    const float* td_wh = (const float*)d_in[5];
    const float* td_bi = (const float*)d_in[6];
    const float* td_bh = (const float*)d_in[7];
    const float* lg_wi = (const float*)d_in[8];
    const float* lg_wh = (const float*)d_in[9];
    const float* lg_bi = (const float*)d_in[10];
    const float* lg_bh = (const float*)d_in[11];
    const float* ar_wi = (const float*)d_in[12];
    const float* ar_wh = (const float*)d_in[13];
    const float* ar_bi = (const float*)d_in[14];
    const float* ar_bh = (const float*)d_in[15];
    const float* arl_w = (const float*)d_in[16];
    const float* arl_b = (const float*)d_in[17];
    const float* out_w = (const float*)d_in[18];
    const float* out_b = (const float*)d_in[19];
    const float* af_w  = (const float*)d_in[20];
    const float* af_b  = (const float*)d_in[21];
    const float* ad_w  = (const float*)d_in[22];
    const float* ad_b  = (const float*)d_in[23];
    const float* aw_w  = (const float*)d_in[24];
    const float* aw_b  = (const float*)d_in[25];
    float* out = (float*)d_out;

    // workspace carve
    float* ws = (float*)d_ws;
    size_t off = 0;
    auto alloc = [&](size_t n) { float* p = ws + off; off += n; return p; };
    float* h1      = alloc((size_t)B * D);
    float* c1      = alloc((size_t)B * D);
    float* h2      = alloc((size_t)B * D);
    float* c2      = alloc((size_t)B * D);
    float* arh     = alloc((size_t)B * D);
    float* arc     = alloc((size_t)B * D);
    float* prev_h1 = alloc((size_t)B * D);
    float* favg    = alloc((size_t)B * F);
    float* embs_s  = alloc((size_t)B * TD * E);
    float* img_att = alloc((size_t)B * NR * A_DIM);
    float* xtd     = alloc((size_t)B * 5120);
    float* xlg     = alloc((size_t)B * 4096);
    float* xar     = alloc((size_t)B * 2048);
    float* gates   = alloc((size_t)B * 4096);
    float* h1a     = alloc((size_t)B * A_DIM);
    float* awe     = alloc((size_t)B * F);
    float* diffb   = alloc((size_t)B * D);
    int* ip     = (int*)(ws + off);
    int* order  = ip; ip += B;
    int* dec_l  = ip; ip += B;
    int* active = ip; ip += TD;
    int* seqs_s = ip; ip += B * T;
    int* rowmap = ip; ip += B * NR;

    float* loss_ptr = out + (size_t)B * TD * V + B * T + B;

    k_sort_init<<<1, B, 0, stream>>>(sizes, sequences, order, dec_l, active, seqs_s, rowmap, out);
    k_zero<<<(7 * B * D + 255) / 256, 256, 0, stream>>>(h1, 7 * B * D);   // h1..prev_h1 contiguous
    k_feats_avg<<<dim3(F / 256, B), 256, 0, stream>>>(feats, order, favg);
    k_emb_gather<<<dim3((TD * E) / 256, B), 256, 0, stream>>>(emb, seqs_s, embs_s);
    // img_att = feats_s @ af_w^T + af_b   (M = 4608 via rowmap)
    k_gemm<<<dim3(B * NR / GBM, A_DIM / GBN), 256, 0, stream>>>(
        feats, rowmap, af_w, F, nullptr, F, af_b, nullptr,
        img_att, A_DIM, A_DIM, 0, nullptr, nullptr);

    for (int t = 0; t < TD; ++t) {
        const int* actp = active + t;
        k_copy<<<512, 256, 0, stream>>>(h1, prev_h1, B * D);
        k_concat_td<<<dim3(20, B), 256, 0, stream>>>(h2, favg, embs_s, h1, xtd, t);
        k_gemm<<<dim3(2, 128), 256, 0, stream>>>(
            xtd, nullptr, td_wi, 4096, td_wh, 5120, td_bi, td_bh,
            gates, 4096, 4096, 0, nullptr, nullptr);
        k_lstm<<<512, 256, 0, stream>>>(gates, h1, c1, actp);
        k_gemm<<<dim3(2, 32), 256, 0, stream>>>(
            h1, nullptr, ad_w, 1024, nullptr, 1024, ad_b, nullptr,
            h1a, 1024, 1024, 0, nullptr, nullptr);
        k_attn<<<B, 256, 0, stream>>>(h1a, img_att, aw_w, aw_b, feats, order, awe);
        k_concat_lg<<<dim3(16, B), 256, 0, stream>>>(awe, h1, h2, xlg);
        k_gemm<<<dim3(2, 128), 256, 0, stream>>>(
            xlg, nullptr, lg_wi, 3072, lg_wh, 4096, lg_bi, lg_bh,
            gates, 4096, 4096, 0, nullptr, nullptr);
        k_lstm<<<512, 256, 0, stream>>>(gates, h2, c2, actp);
        k_concat_ar<<<dim3(8, B), 256, 0, stream>>>(h1, arh, xar);
        k_gemm<<<dim3(2, 128), 256, 0, stream>>>(
            xar, nullptr, ar_wi, 1024, ar_wh, 2048, ar_bi, ar_bh,
            gates, 4096, 4096, 0, nullptr, nullptr);
        k_lstm<<<512, 256, 0, stream>>>(gates, arh, arc, actp);
        // diff = arh @ arl_w^T + arl_b - prev_h1
        k_gemm<<<dim3(2, 32), 256, 0, stream>>>(
            arh, nullptr, arl_w, 1024, nullptr, 1024, arl_b, nullptr,
            diffb, 1024, 1024, 1, prev_h1, nullptr);
        if (t > 0) k_loss<<<B, 256, 0, stream>>>(diffb, actp, loss_ptr);
        // preds[:, t, :] = mask * (h2 @ out_w^T + out_b)
        k_gemm<<<dim3(2, (V + GBN - 1) / GBN), 256, 0, stream>>>(
            h2, nullptr, out_w, 1024, nullptr, 1024, out_b, nullptr,
            out + (size_t)t * V, TD * V, V, 2, nullptr, actp);
    }
}

// Round 2
// 8004.121 us; speedup vs baseline: 2.0151x; 2.0151x over previous
//
#include <hip/hip_runtime.h>
#include <math.h>

#define B    128
#define T    20
#define TD   19      // Tdec
#define V    10000
#define D    1024
#define E    1024
#define A_DIM 1024
#define F    2048
#define NR   36

typedef __attribute__((ext_vector_type(8))) short bf16x8;
typedef __attribute__((ext_vector_type(4))) float f32x4;

__device__ __forceinline__ float sigm(float x) { return 1.f / (1.f + __expf(-x)); }

// f32 -> bf16 round-to-nearest-even (finite inputs)
__device__ __forceinline__ unsigned short f2bf(float f) {
    union { float f; unsigned u; } x; x.f = f;
    unsigned r = x.u + 0x7fffu + ((x.u >> 16) & 1u);
    return (unsigned short)(r >> 16);
}

// ---------------------------------------------------------------------------
// Sort (stable descending by sizes), seqs/order outputs, active counts, rowmap
// ---------------------------------------------------------------------------
__global__ void k_sort_init(const int* __restrict__ sizes,
                            const int* __restrict__ sequences,
                            int* __restrict__ order,
                            int* __restrict__ dec_len,
                            int* __restrict__ active,
                            int* __restrict__ seqs_s,
                            int* __restrict__ rowmap,
                            float* __restrict__ out)
{
    int tid = threadIdx.x;                // 128 threads
    __shared__ int s_sizes[B];
    __shared__ int s_dl[B];
    s_sizes[tid] = sizes[tid];
    __syncthreads();
    int si = s_sizes[tid];
    int rank = 0;
    for (int j = 0; j < B; ++j) {
        int sj = s_sizes[j];
        if (sj > si || (sj == si && j < tid)) rank++;
    }
    order[rank] = tid;
    __syncthreads();
    int ob = order[tid];
    int dl = s_sizes[ob] - 1;
    dec_len[tid] = dl;
    s_dl[tid] = dl;
    for (int tt = 0; tt < T; ++tt) {
        int sq = sequences[ob * T + tt];
        seqs_s[tid * T + tt] = sq;
        out[(size_t)B * TD * V + tid * T + tt] = (float)sq;
    }
    out[(size_t)B * TD * V + B * T + tid] = (float)ob;
    __syncthreads();
    if (tid < TD) {
        int c = 0;
        for (int b = 0; b < B; ++b) c += (s_dl[b] > tid) ? 1 : 0;
        active[tid] = c;
    }
    for (int m = tid; m < B * NR; m += B)
        rowmap[m] = order[m / NR] * NR + (m % NR);
    if (tid == 0) out[(size_t)B * TD * V + B * T + B] = 0.f;   // loss accumulator
}

__global__ void k_zero(float* __restrict__ p, int n) {
    int i = blockIdx.x * 256 + threadIdx.x;
    if (i < n) p[i] = 0.f;
}

// featsAvg[b][f] = mean_r feats[order[b]][r][f]
__global__ void k_feats_avg(const float* __restrict__ feats, const int* __restrict__ order,
                            float* __restrict__ favg)
{
    int f = blockIdx.x * 256 + threadIdx.x;   // grid.x = 8
    int b = blockIdx.y;
    int ob = order[b];
    const float* base = feats + (size_t)ob * NR * F + f;
    float s = 0.f;
    for (int r = 0; r < NR; ++r) s += base[(size_t)r * F];
    favg[b * F + f] = s * (1.f / NR);
}

// embs_s[b][t][e] = emb[seqs_s[b][t]][e], t < TD
__global__ void k_emb_gather(const float* __restrict__ emb, const int* __restrict__ seqs_s,
                             float* __restrict__ embs_s)
{
    int j = blockIdx.x * 256 + threadIdx.x;   // 0..TD*E-1, grid.x = 76
    int b = blockIdx.y;
    int t = j >> 10, e = j & 1023;
    embs_s[((size_t)b * TD + t) * E + e] = emb[(size_t)seqs_s[b * T + t] * E + e];
}

// concat builders (f32)
__global__ void k_concat_td(const float* __restrict__ h2, const float* __restrict__ favg,
                            const float* __restrict__ embs_s, const float* __restrict__ h1,
                            float* __restrict__ xtd, int t)
{
    int k = blockIdx.x * 256 + threadIdx.x;   // grid.x = 20
    int b = blockIdx.y;
    float v;
    if (k < 1024)      v = h2[b * 1024 + k];
    else if (k < 3072) v = favg[b * 2048 + (k - 1024)];
    else if (k < 4096) v = embs_s[((size_t)b * TD + t) * 1024 + (k - 3072)];
    else               v = h1[b * 1024 + (k - 4096)];
    xtd[(size_t)b * 5120 + k] = v;
}

__global__ void k_concat_lg(const float* __restrict__ awe, const float* __restrict__ h1,
                            const float* __restrict__ h2, float* __restrict__ xlg)
{
    int k = blockIdx.x * 256 + threadIdx.x;   // grid.x = 16
    int b = blockIdx.y;
    float v;
    if (k < 2048)      v = awe[b * 2048 + k];
    else if (k < 3072) v = h1[b * 1024 + (k - 2048)];
    else               v = h2[b * 1024 + (k - 3072)];
    xlg[(size_t)b * 4096 + k] = v;
}

__global__ void k_concat_ar(const float* __restrict__ h1, const float* __restrict__ arh,
                            float* __restrict__ xar)
{
    int k = blockIdx.x * 256 + threadIdx.x;   // grid.x = 8
    int b = blockIdx.y;
    xar[(size_t)b * 2048 + k] = (k < 1024) ? h1[b * 1024 + k] : arh[b * 1024 + (k - 1024)];
}

// ---------------------------------------------------------------------------
// MFMA bf16 GEMM: C[m][n] = sum_k A[m][k]*W[n][k] (+bias (+bias2))
//   A f32 [M x Ktot] row-major (optional rowmap), W f32 rows split [W1(K1)|W2]
//   inline f32->bf16 conversion during LDS staging.
//   Tile M=128 x N=32, BK=64, 256 threads (4 waves).
//   Wave w computes m-tiles {2w,2w+1} x n-tiles {0,1} (16x16 each).
//   LDS layout fragment-contiguous: granule(16B) index = (tile*2+subk)*64+lane.
//   modes: 0 plain; 1 store v - sub[row*1024+col]; 2 zero rows >= *actp
// ---------------------------------------------------------------------------
__global__ __launch_bounds__(256)
void k_gemm(const float* __restrict__ Amat, const int* __restrict__ rowmap,
            const float* __restrict__ W1, int K1,
            const float* __restrict__ W2, int Ktot,
            const float* __restrict__ bias, const float* __restrict__ bias2,
            float* __restrict__ C, int ldc, int N,
            int mode, const float* __restrict__ sub, const int* __restrict__ actp)
{
    __shared__ __align__(16) unsigned short As[8 * 2 * 64 * 8];   // 16 KB
    __shared__ __align__(16) unsigned short Ws[2 * 2 * 64 * 8];   // 4 KB

    int tid = threadIdx.x;
    int bn = blockIdx.x * 32;
    int bm = blockIdx.y * 128;
    int lane = tid & 63;
    int w = tid >> 6;
    int K2 = Ktot - K1;

    // staging decomposition: granule index l -> row = l>>3, gk = l&7 (k = gk*8..+7)
    int agk  = tid & 7;
    int asub = agk >> 2, ag = agk & 3;

    const float* arow[4];
    int adst[4];
#pragma unroll
    for (int i = 0; i < 4; ++i) {
        int r = (tid >> 3) + 32 * i;
        int gr = bm + r;
        if (rowmap) gr = rowmap[gr];
        arow[i] = Amat + (size_t)gr * Ktot + agk * 8;
        int mt = r >> 4, rr = r & 15;
        adst[i] = ((mt * 2 + asub) * 64 + ag * 16 + rr) * 8;
    }
    int nrow = bn + (tid >> 3);
    bool wv = nrow < N;
    const float* wrow1 = wv ? (W1 + (size_t)nrow * K1 + agk * 8) : W1;
    const float* wrow2 = (wv && W2) ? (W2 + (size_t)nrow * K2 + agk * 8) : W2;
    int wnt = (tid >> 3) >> 4, wrn = (tid >> 3) & 15;
    int wdst = ((wnt * 2 + asub) * 64 + ag * 16 + wrn) * 8;

    f32x4 acc[2][2] = {};

    for (int k0 = 0; k0 < Ktot; k0 += 64) {
        float4 av[4][2];
#pragma unroll
        for (int i = 0; i < 4; ++i) {
            av[i][0] = *(const float4*)(arow[i] + k0);
            av[i][1] = *(const float4*)(arow[i] + k0 + 4);
        }
        float4 wv0 = make_float4(0.f, 0.f, 0.f, 0.f), wv1 = wv0;
        if (k0 < K1) {
            if (wv) { wv0 = *(const float4*)(wrow1 + k0); wv1 = *(const float4*)(wrow1 + k0 + 4); }
        } else {
            if (wv && W2) { wv0 = *(const float4*)(wrow2 + (k0 - K1)); wv1 = *(const float4*)(wrow2 + (k0 - K1) + 4); }
        }
        __syncthreads();
#pragma unroll
        for (int i = 0; i < 4; ++i) {
            unsigned short* d = As + adst[i];
            d[0] = f2bf(av[i][0].x); d[1] = f2bf(av[i][0].y);
            d[2] = f2bf(av[i][0].z); d[3] = f2bf(av[i][0].w);
            d[4] = f2bf(av[i][1].x); d[5] = f2bf(av[i][1].y);
            d[6] = f2bf(av[i][1].z); d[7] = f2bf(av[i][1].w);
        }
        {
            unsigned short* d = Ws + wdst;
            d[0] = f2bf(wv0.x); d[1] = f2bf(wv0.y); d[2] = f2bf(wv0.z); d[3] = f2bf(wv0.w);
            d[4] = f2bf(wv1.x); d[5] = f2bf(wv1.y); d[6] = f2bf(wv1.z); d[7] = f2bf(wv1.w);
        }
        __syncthreads();
#pragma unroll
        for (int subk = 0; subk < 2; ++subk) {
            bf16x8 a0 = *(const bf16x8*)(As + (((2 * w + 0) * 2 + subk) * 64 + lane) * 8);
            bf16x8 a1 = *(const bf16x8*)(As + (((2 * w + 1) * 2 + subk) * 64 + lane) * 8);
            bf16x8 b0 = *(const bf16x8*)(Ws + ((0 * 2 + subk) * 64 + lane) * 8);
            bf16x8 b1 = *(const bf16x8*)(Ws + ((1 * 2 + subk) * 64 + lane) * 8);
            acc[0][0] = __builtin_amdgcn_mfma_f32_16x16x32_bf16(a0, b0, acc[0][0], 0, 0, 0);
            acc[0][1] = __builtin_amdgcn_mfma_f32_16x16x32_bf16(a0, b1, acc[0][1], 0, 0, 0);
            acc[1][0] = __builtin_amdgcn_mfma_f32_16x16x32_bf16(a1, b0, acc[1][0], 0, 0, 0);
            acc[1][1] = __builtin_amdgcn_mfma_f32_16x16x32_bf16(a1, b1, acc[1][1], 0, 0, 0);
        }
    }

    int act = (mode == 2) ? *actp : (1 << 30);
    int rg4 = (lane >> 4) * 4;
    int cc = lane & 15;
#pragma unroll
    for (int mi = 0; mi < 2; ++mi) {
        int mt = 2 * w + mi;
#pragma unroll
        for (int ni = 0; ni < 2; ++ni) {
            int col = bn + ni * 16 + cc;
            if (col >= N) continue;
            float bb = bias[col];
            if (bias2) bb += bias2[col];
#pragma unroll
            for (int rg = 0; rg < 4; ++rg) {
                int row = bm + mt * 16 + rg4 + rg;
                float v = acc[mi][ni][rg] + bb;
                if (mode == 1) v -= sub[(size_t)row * 1024 + col];
                if (mode == 2 && row >= act) v = 0.f;
                C[(size_t)row * ldc + col] = v;
            }
        }
    }
}

// LSTM pointwise; optionally captures pre-update h into prevh (active rows only;
// frozen rows' prev is only consumed masked, so staleness is harmless)
__global__ void k_lstm(const float* __restrict__ gates, float* __restrict__ h,
                       float* __restrict__ c, const int* __restrict__ actp,
                       float* __restrict__ prevh)
{
    int idx = blockIdx.x * 256 + threadIdx.x;   // 131072, grid 512
    int b = idx >> 10;
    if (b >= *actp) return;                     // frozen rows: skip write
    int n = idx & 1023;
    const float* g = gates + (size_t)b * 4096;
    float gi = g[n], gf = g[1024 + n], gg = g[2048 + n], go = g[3072 + n];
    if (prevh) prevh[idx] = h[idx];
    float cc = c[idx];
    float c2 = sigm(gf) * cc + sigm(gi) * tanhf(gg);
    c[idx] = c2;
    h[idx] = sigm(go) * tanhf(c2);
}

// attention: e = relu(h1a + img_att) . aw_w + aw_b ; softmax over 36 ; awe = alpha^T feats
__global__ __launch_bounds__(256)
void k_attn(const float* __restrict__ h1a, const float* __restrict__ img_att,
            const float* __restrict__ aw_w, const float* __restrict__ aw_b,
            const float* __restrict__ feats, const int* __restrict__ order,
            float* __restrict__ awe)
{
    int b = blockIdx.x;
    int tid = threadIdx.x;
    __shared__ float sh[A_DIM];
    __shared__ float se[NR];
    for (int i = tid; i < A_DIM; i += 256) sh[i] = h1a[b * A_DIM + i];
    __syncthreads();
    int wid = tid >> 6, lane = tid & 63;
    for (int r = wid; r < NR; r += 4) {
        const float* row = img_att + ((size_t)b * NR + r) * A_DIM;
        float s = 0.f;
        for (int a = lane; a < A_DIM; a += 64)
            s += fmaxf(sh[a] + row[a], 0.f) * aw_w[a];
        for (int off = 32; off > 0; off >>= 1) s += __shfl_down(s, off, 64);
        if (lane == 0) se[r] = s + aw_b[0];
    }
    __syncthreads();
    if (tid == 0) {
        float m = se[0];
        for (int r = 1; r < NR; ++r) m = fmaxf(m, se[r]);
        float ssum = 0.f;
        for (int r = 0; r < NR; ++r) { float ex = __expf(se[r] - m); se[r] = ex; ssum += ex; }
        float inv = 1.f / ssum;
        for (int r = 0; r < NR; ++r) se[r] *= inv;
    }
    __syncthreads();
    int ob = order[b];
    const float* fb = feats + (size_t)ob * NR * F;
    for (int f = tid; f < F; f += 256) {
        float s = 0.f;
        for (int r = 0; r < NR; ++r) s += se[r] * fb[(size_t)r * F + f];
        awe[b * F + f] = s;
    }
}

// loss += sum_b<act ||diff_b||^2 * 0.005 / act
__global__ void k_loss(const float* __restrict__ diff, const int* __restrict__ actp,
                       float* __restrict__ loss)
{
    int b = blockIdx.x;
    int act = *actp;
    if (b >= act) return;
    int tid = threadIdx.x;
    float s = 0.f;
    for (int d = tid; d < D; d += 256) { float v = diff[b * D + d]; s += v * v; }
    for (int off = 32; off > 0; off >>= 1) s += __shfl_down(s, off, 64);
    __shared__ float ps[4];
    int wid = tid >> 6, lane = tid & 63;
    if (lane == 0) ps[wid] = s;
    __syncthreads();
    if (tid == 0) {
        float tot = ps[0] + ps[1] + ps[2] + ps[3];
        atomicAdd(loss, tot * (0.005f / (float)act));
    }
}

// ---------------------------------------------------------------------------
extern "C" void kernel_launch(void* const* d_in, const int* in_sizes, int n_in,
                              void* d_out, int out_size, void* d_ws, size_t ws_size,
                              hipStream_t stream)
{
    const float* feats     = (const float*)d_in[0];
    const int*   sequences = (const int*)d_in[1];
    const int*   sizes     = (const int*)d_in[2];
    const float* emb       = (const float*)d_in[3];
    const float* td_wi = (const float*)d_in[4];
    const float* td_wh = (const float*)d_in[5];
    const float* td_bi = (const float*)d_in[6];
    const float* td_bh = (const float*)d_in[7];
    const float* lg_wi = (const float*)d_in[8];
    const float* lg_wh = (const float*)d_in[9];
    const float* lg_bi = (const float*)d_in[10];
    const float* lg_bh = (const float*)d_in[11];
    const float* ar_wi = (const float*)d_in[12];
    const float* ar_wh = (const float*)d_in[13];
    const float* ar_bi = (const float*)d_in[14];
    const float* ar_bh = (const float*)d_in[15];
    const float* arl_w = (const float*)d_in[16];
    const float* arl_b = (const float*)d_in[17];
    const float* out_w = (const float*)d_in[18];
    const float* out_b = (const float*)d_in[19];
    const float* af_w  = (const float*)d_in[20];
    const float* af_b  = (const float*)d_in[21];
    const float* ad_w  = (const float*)d_in[22];
    const float* ad_b  = (const float*)d_in[23];
    const float* aw_w  = (const float*)d_in[24];
    const float* aw_b  = (const float*)d_in[25];
    float* out = (float*)d_out;

    // workspace carve
    float* ws = (float*)d_ws;
    size_t off = 0;
    auto alloc = [&](size_t n) { float* p = ws + off; off += n; return p; };
    float* h1      = alloc((size_t)B * D);
    float* c1      = alloc((size_t)B * D);
    float* h2      = alloc((size_t)B * D);
    float* c2      = alloc((size_t)B * D);
    float* arh     = alloc((size_t)B * D);
    float* arc     = alloc((size_t)B * D);
    float* prev_h1 = alloc((size_t)B * D);
    float* favg    = alloc((size_t)B * F);
    float* embs_s  = alloc((size_t)B * TD * E);
    float* img_att = alloc((size_t)B * NR * A_DIM);
    float* xtd     = alloc((size_t)B * 5120);
    float* xlg     = alloc((size_t)B * 4096);
    float* xar     = alloc((size_t)B * 2048);
    float* gates   = alloc((size_t)B * 4096);
    float* h1a     = alloc((size_t)B * A_DIM);
    float* awe     = alloc((size_t)B * F);
    float* diffb   = alloc((size_t)B * D);
    int* ip     = (int*)(ws + off);
    int* order  = ip; ip += B;
    int* dec_l  = ip; ip += B;
    int* active = ip; ip += TD;
    int* seqs_s = ip; ip += B * T;
    int* rowmap = ip; ip += B * NR;

    float* loss_ptr = out + (size_t)B * TD * V + B * T + B;

    k_sort_init<<<1, B, 0, stream>>>(sizes, sequences, order, dec_l, active, seqs_s, rowmap, out);
    k_zero<<<(7 * B * D + 255) / 256, 256, 0, stream>>>(h1, 7 * B * D);   // h1..prev_h1 contiguous
    k_feats_avg<<<dim3(F / 256, B), 256, 0, stream>>>(feats, order, favg);
    k_emb_gather<<<dim3((TD * E) / 256, B), 256, 0, stream>>>(emb, seqs_s, embs_s);
    // img_att = feats_s @ af_w^T + af_b   (M = 4608 via rowmap)
    k_gemm<<<dim3(A_DIM / 32, NR), 256, 0, stream>>>(
        feats, rowmap, af_w, F, nullptr, F, af_b, nullptr,
        img_att, A_DIM, A_DIM, 0, nullptr, nullptr);

    for (int t = 0; t < TD; ++t) {
        const int* actp = active + t;
        k_concat_td<<<dim3(20, B), 256, 0, stream>>>(h2, favg, embs_s, h1, xtd, t);
        k_gemm<<<dim3(128, 1), 256, 0, stream>>>(
            xtd, nullptr, td_wi, 4096, td_wh, 5120, td_bi, td_bh,
            gates, 4096, 4096, 0, nullptr, nullptr);
        k_lstm<<<512, 256, 0, stream>>>(gates, h1, c1, actp, prev_h1);
        k_gemm<<<dim3(32, 1), 256, 0, stream>>>(
            h1, nullptr, ad_w, 1024, nullptr, 1024, ad_b, nullptr,
            h1a, 1024, 1024, 0, nullptr, nullptr);
        k_attn<<<B, 256, 0, stream>>>(h1a, img_att, aw_w, aw_b, feats, order, awe);
        k_concat_lg<<<dim3(16, B), 256, 0, stream>>>(awe, h1, h2, xlg);
        k_gemm<<<dim3(128, 1), 256, 0, stream>>>(
            xlg, nullptr, lg_wi, 3072, lg_wh, 4096, lg_bi, lg_bh,
            gates, 4096, 4096, 0, nullptr, nullptr);
        k_lstm<<<512, 256, 0, stream>>>(gates, h2, c2, actp, nullptr);
        k_concat_ar<<<dim3(8, B), 256, 0, stream>>>(h1, arh, xar);
        k_gemm<<<dim3(128, 1), 256, 0, stream>>>(
            xar, nullptr, ar_wi, 1024, ar_wh, 2048, ar_bi, ar_bh,
            gates, 4096, 4096, 0, nullptr, nullptr);
        k_lstm<<<512, 256, 0, stream>>>(gates, arh, arc, actp, nullptr);
        // diff = arh @ arl_w^T + arl_b - prev_h1
        k_gemm<<<dim3(32, 1), 256, 0, stream>>>(
            arh, nullptr, arl_w, 1024, nullptr, 1024, arl_b, nullptr,
            diffb, 1024, 1024, 1, prev_h1, nullptr);
        if (t > 0) k_loss<<<B, 256, 0, stream>>>(diffb, actp, loss_ptr);
        // preds[:, t, :] = mask * (h2 @ out_w^T + out_b)
        k_gemm<<<dim3((V + 31) / 32, 1), 256, 0, stream>>>(
            h2, nullptr, out_w, 1024, nullptr, 1024, out_b, nullptr,
            out + (size_t)t * V, TD * V, V, 2, nullptr, actp);
    }
}

// Round 3
// 6430.173 us; speedup vs baseline: 2.5083x; 1.2448x over previous
//
#include <hip/hip_runtime.h>
#include <math.h>

#define B    128
#define T    20
#define TD   19      // Tdec
#define V    10000
#define D    1024
#define E    1024
#define A_DIM 1024
#define F    2048
#define NR   36

typedef __attribute__((ext_vector_type(8))) short bf16x8;
typedef __attribute__((ext_vector_type(4))) float f32x4;

__device__ __forceinline__ float sigm(float x) { return 1.f / (1.f + __expf(-x)); }

__device__ __forceinline__ unsigned short f2bf(float f) {
    union { float f; unsigned u; } x; x.f = f;
    unsigned r = x.u + 0x7fffu + ((x.u >> 16) & 1u);
    return (unsigned short)(r >> 16);
}
__device__ __forceinline__ float bf2f(unsigned short u) {
    union { float f; unsigned u; } x; x.u = ((unsigned)u) << 16; return x.f;
}
__device__ __forceinline__ uint4 pack8(const float* __restrict__ src) {
    float4 a = *(const float4*)src, b = *(const float4*)(src + 4);
    union { unsigned short u[8]; uint4 v; } p;
    p.u[0] = f2bf(a.x); p.u[1] = f2bf(a.y); p.u[2] = f2bf(a.z); p.u[3] = f2bf(a.w);
    p.u[4] = f2bf(b.x); p.u[5] = f2bf(b.y); p.u[6] = f2bf(b.z); p.u[7] = f2bf(b.w);
    return p.v;
}

// ---------------------------------------------------------------------------
// Sort (stable descending by sizes), seqs/order outputs, active counts
// ---------------------------------------------------------------------------
__global__ void k_sort_init(const int* __restrict__ sizes,
                            const int* __restrict__ sequences,
                            int* __restrict__ order,
                            int* __restrict__ active,
                            int* __restrict__ seqs_s,
                            float* __restrict__ out)
{
    int tid = threadIdx.x;                // 128 threads
    __shared__ int s_sizes[B];
    __shared__ int s_dl[B];
    s_sizes[tid] = sizes[tid];
    __syncthreads();
    int si = s_sizes[tid];
    int rank = 0;
    for (int j = 0; j < B; ++j) {
        int sj = s_sizes[j];
        if (sj > si || (sj == si && j < tid)) rank++;
    }
    order[rank] = tid;
    __syncthreads();
    int ob = order[tid];
    int dl = s_sizes[ob] - 1;
    s_dl[tid] = dl;
    for (int tt = 0; tt < T; ++tt) {
        int sq = sequences[ob * T + tt];
        seqs_s[tid * T + tt] = sq;
        out[(size_t)B * TD * V + tid * T + tt] = (float)sq;
    }
    out[(size_t)B * TD * V + B * T + tid] = (float)ob;
    __syncthreads();
    if (tid < TD) {
        int c = 0;
        for (int b = 0; b < B; ++b) c += (s_dl[b] > tid) ? 1 : 0;
        active[tid] = c;
    }
    if (tid == 0) out[(size_t)B * TD * V + B * T + B] = 0.f;   // loss accumulator
}

__global__ void k_zero(float* __restrict__ p, int n) {
    int i = blockIdx.x * 256 + threadIdx.x;
    if (i < n) p[i] = 0.f;
}

// weight f32 -> bf16, rows concatenated [s1 row (K1) | s2 row (K2)]
__global__ void k_w2bf(const float* __restrict__ s1, int K1,
                       const float* __restrict__ s2, int K2,
                       unsigned short* __restrict__ dst, long total /*granules*/)
{
    long g = (long)blockIdx.x * 256 + threadIdx.x;
    if (g >= total) return;
    int Kt = K1 + K2;
    int gpr = Kt >> 3;
    int row = (int)(g / gpr);
    int k8 = (int)(g % gpr) << 3;
    const float* src = (k8 < K1) ? (s1 + (size_t)row * K1 + k8)
                                 : (s2 + (size_t)row * K2 + (k8 - K1));
    *(uint4*)(dst + ((size_t)g << 3)) = pack8(src);
}

// feats (sorted by order) -> bf16 [4608 x 2048]
__global__ void k_feats2bf(const float* __restrict__ feats, const int* __restrict__ order,
                           unsigned short* __restrict__ dst)
{
    long g = (long)blockIdx.x * 256 + threadIdx.x;   // 4608*256 granules
    int row = (int)(g >> 8);
    int k8 = ((int)g & 255) << 3;
    int b = row / NR, r = row - b * NR;
    const float* src = feats + ((size_t)order[b] * NR + r) * F + k8;
    *(uint4*)(dst + (size_t)row * F + k8) = pack8(src);
}

// featsAvg -> bf16 directly into xtd slot [1024,3072)
__global__ void k_favg(const float* __restrict__ feats, const int* __restrict__ order,
                       unsigned short* __restrict__ xtd)
{
    int idx = blockIdx.x * 256 + threadIdx.x;   // B*F = 262144
    int b = idx >> 11, f = idx & 2047;
    const float* base = feats + (size_t)order[b] * NR * F + f;
    float s = 0.f;
#pragma unroll
    for (int r = 0; r < NR; ++r) s += base[(size_t)r * F];
    xtd[(size_t)b * 5120 + 1024 + f] = f2bf(s * (1.f / NR));
}

// embeddings (sorted) -> bf16 [B x TD x 1024]
__global__ void k_emb2bf(const float* __restrict__ emb, const int* __restrict__ seqs_s,
                         unsigned short* __restrict__ embs_bf)
{
    long g = (long)blockIdx.x * 256 + threadIdx.x;  // B*TD*128 granules
    if (g >= (long)B * TD * 128) return;
    int b = (int)(g / (TD * 128));
    int rem = (int)(g - (long)b * (TD * 128));
    int t = rem >> 7, e8 = (rem & 127) << 3;
    const float* src = emb + (size_t)seqs_s[b * T + t] * E + e8;
    *(uint4*)(embs_bf + (((size_t)(b * TD + t)) << 10) + e8) = pack8(src);
}

// copy embs_bf[:,t,:] into xtd emb slot [3072,4096)
__global__ void k_embslot(const unsigned short* __restrict__ embs_bf,
                          unsigned short* __restrict__ xtd, int t)
{
    int g = blockIdx.x * 256 + threadIdx.x;  // B*128 = 16384
    int b = g >> 7, e8 = (g & 127) << 3;
    *(uint4*)(xtd + (size_t)b * 5120 + 3072 + e8) =
        *(const uint4*)(embs_bf + (((size_t)(b * TD + t)) << 10) + e8);
}

// ---------------------------------------------------------------------------
// MFMA bf16 GEMM: C[m][n] = sum_k A[m][k]*W[n][k] (+bias (+bias2))
//   A bf16 [M x lda], W bf16 [N x K] row-major K-contiguous.
//   Tile M=128 x N=32, BK=64, 256 threads (4 waves).
//   LDS fragment-contiguous granules; staging via global_load_lds (16B).
//   modes: 0 plain store; 1 ARNet loss (no store): sum (acc+bias-sub)^2 over
//          rows<act -> atomicAdd(lossp, *0.005/act); 2 store, zero rows>=act.
// ---------------------------------------------------------------------------
__global__ __launch_bounds__(256)
void k_gemm(const unsigned short* __restrict__ A, int lda,
            const unsigned short* __restrict__ W, int K,
            const float* __restrict__ bias, const float* __restrict__ bias2,
            float* __restrict__ C, int ldc, int N,
            int mode, const float* __restrict__ sub, const int* __restrict__ actp,
            float* __restrict__ lossp)
{
    __shared__ __align__(16) unsigned short As[16 * 512];   // 16 KB
    __shared__ __align__(16) unsigned short Ws[4 * 512];    // 4 KB
    __shared__ float ps[4];

    int tid = threadIdx.x, l = tid & 63, w = tid >> 6;
    int bn = blockIdx.x * 32, bm = blockIdx.y * 128;
    int rsel = l & 15, ksel = (l >> 4) * 8;

    const unsigned short* ap[4];
#pragma unroll
    for (int i = 0; i < 4; ++i) {
        int s = 4 * w + i, mt = s >> 1, subk = s & 1;
        ap[i] = A + (size_t)(bm + mt * 16 + rsel) * lda + subk * 32 + ksel;
    }
    int nt = w >> 1, wsub = w & 1;
    int nr = bn + nt * 16 + rsel; if (nr >= N) nr = N - 1;
    const unsigned short* wp = W + (size_t)nr * K + wsub * 32 + ksel;

    f32x4 acc[2][2] = {};

    for (int k0 = 0; k0 < K; k0 += 64) {
        __syncthreads();
#pragma unroll
        for (int i = 0; i < 4; ++i)
            __builtin_amdgcn_global_load_lds(
                (const __attribute__((address_space(1))) unsigned int*)(ap[i]),
                (__attribute__((address_space(3))) unsigned int*)(As + (4 * w + i) * 512),
                16, 0, 0);
        __builtin_amdgcn_global_load_lds(
            (const __attribute__((address_space(1))) unsigned int*)(wp),
            (__attribute__((address_space(3))) unsigned int*)(Ws + w * 512),
            16, 0, 0);
        ap[0] += 64; ap[1] += 64; ap[2] += 64; ap[3] += 64; wp += 64;
        __syncthreads();
#pragma unroll
        for (int subk = 0; subk < 2; ++subk) {
            bf16x8 a0 = *(const bf16x8*)(As + (4 * w + subk) * 512 + l * 8);
            bf16x8 a1 = *(const bf16x8*)(As + (4 * w + 2 + subk) * 512 + l * 8);
            bf16x8 b0 = *(const bf16x8*)(Ws + subk * 512 + l * 8);
            bf16x8 b1 = *(const bf16x8*)(Ws + (2 + subk) * 512 + l * 8);
            acc[0][0] = __builtin_amdgcn_mfma_f32_16x16x32_bf16(a0, b0, acc[0][0], 0, 0, 0);
            acc[0][1] = __builtin_amdgcn_mfma_f32_16x16x32_bf16(a0, b1, acc[0][1], 0, 0, 0);
            acc[1][0] = __builtin_amdgcn_mfma_f32_16x16x32_bf16(a1, b0, acc[1][0], 0, 0, 0);
            acc[1][1] = __builtin_amdgcn_mfma_f32_16x16x32_bf16(a1, b1, acc[1][1], 0, 0, 0);
        }
    }

    int rg4 = (l >> 4) * 4, cc = l & 15;
    if (mode == 1) {
        int act = *actp;
        float s = 0.f;
#pragma unroll
        for (int mi = 0; mi < 2; ++mi) {
            int mt = 2 * w + mi;
#pragma unroll
            for (int ni = 0; ni < 2; ++ni) {
                int col = bn + ni * 16 + cc;
                float bb = bias[col];
#pragma unroll
                for (int rg = 0; rg < 4; ++rg) {
                    int row = bm + mt * 16 + rg4 + rg;
                    float v = acc[mi][ni][rg] + bb - sub[(size_t)row * 1024 + col];
                    if (row < act) s += v * v;
                }
            }
        }
        for (int o = 32; o > 0; o >>= 1) s += __shfl_down(s, o, 64);
        if (l == 0) ps[w] = s;
        __syncthreads();
        if (tid == 0) {
            float tot = ps[0] + ps[1] + ps[2] + ps[3];
            atomicAdd(lossp, tot * (0.005f / (float)act));
        }
        return;
    }

    int act = (mode == 2) ? *actp : (1 << 30);
#pragma unroll
    for (int mi = 0; mi < 2; ++mi) {
        int mt = 2 * w + mi;
#pragma unroll
        for (int ni = 0; ni < 2; ++ni) {
            int col = bn + ni * 16 + cc;
            if (col >= N) continue;
            float bb = bias[col];
            if (bias2) bb += bias2[col];
#pragma unroll
            for (int rg = 0; rg < 4; ++rg) {
                int row = bm + mt * 16 + rg4 + rg;
                float v = acc[mi][ni][rg] + bb;
                if (mode == 2 && row >= act) v = 0.f;
                C[(size_t)row * ldc + col] = v;
            }
        }
    }
}

// LSTM pointwise: h,c update; optional prevh capture; bf16 h into up to 3 slots
__global__ void k_lstm(const float* __restrict__ gates, float* __restrict__ h,
                       float* __restrict__ c, const int* __restrict__ actp,
                       float* __restrict__ prevh,
                       unsigned short* __restrict__ s1, int ld1,
                       unsigned short* __restrict__ s2, int ld2,
                       unsigned short* __restrict__ s3, int ld3)
{
    int idx = blockIdx.x * 256 + threadIdx.x;   // 131072
    int b = idx >> 10;
    if (b >= *actp) return;                     // frozen rows keep state + slots
    int n = idx & 1023;
    const float* g = gates + ((size_t)b << 12);
    float gi = g[n], gf = g[1024 + n], gg = g[2048 + n], go = g[3072 + n];
    if (prevh) prevh[idx] = h[idx];
    float cc = c[idx];
    float c2 = sigm(gf) * cc + sigm(gi) * tanhf(gg);
    c[idx] = c2;
    float hv = sigm(go) * tanhf(c2);
    h[idx] = hv;
    unsigned short hb = f2bf(hv);
    if (s1) s1[(size_t)b * ld1 + n] = hb;
    if (s2) s2[(size_t)b * ld2 + n] = hb;
    if (s3) s3[(size_t)b * ld3 + n] = hb;
}

// attention: e = relu(h1a + img_att).aw_w + aw_b ; softmax over 36 ;
// awe = alpha^T feats_bf -> bf16 into xlg slot [0,2048)
__global__ __launch_bounds__(256)
void k_attn(const float* __restrict__ h1a, const float* __restrict__ img_att,
            const float* __restrict__ aw_w, const float* __restrict__ aw_b,
            const unsigned short* __restrict__ feats_bf,
            unsigned short* __restrict__ xlg)
{
    int b = blockIdx.x;
    int tid = threadIdx.x;
    __shared__ float sh[A_DIM];
    __shared__ float se[NR];
    for (int i = tid; i < A_DIM; i += 256) sh[i] = h1a[b * A_DIM + i];
    __syncthreads();
    int wid = tid >> 6, lane = tid & 63;
    for (int r = wid; r < NR; r += 4) {
        const float* row = img_att + ((size_t)b * NR + r) * A_DIM;
        float s = 0.f;
        for (int a = lane; a < A_DIM; a += 64)
            s += fmaxf(sh[a] + row[a], 0.f) * aw_w[a];
        for (int off = 32; off > 0; off >>= 1) s += __shfl_down(s, off, 64);
        if (lane == 0) se[r] = s + aw_b[0];
    }
    __syncthreads();
    if (tid == 0) {
        float m = se[0];
        for (int r = 1; r < NR; ++r) m = fmaxf(m, se[r]);
        float ssum = 0.f;
        for (int r = 0; r < NR; ++r) { float ex = __expf(se[r] - m); se[r] = ex; ssum += ex; }
        float inv = 1.f / ssum;
        for (int r = 0; r < NR; ++r) se[r] *= inv;
    }
    __syncthreads();
    const unsigned short* fb = feats_bf + (size_t)b * NR * F;
    for (int f = tid; f < F; f += 256) {
        float s = 0.f;
        for (int r = 0; r < NR; ++r) s += se[r] * bf2f(fb[(size_t)r * F + f]);
        xlg[(size_t)b * 4096 + f] = f2bf(s);
    }
}

// ---------------------------------------------------------------------------
extern "C" void kernel_launch(void* const* d_in, const int* in_sizes, int n_in,
                              void* d_out, int out_size, void* d_ws, size_t ws_size,
                              hipStream_t stream)
{
    const float* feats     = (const float*)d_in[0];
    const int*   sequences = (const int*)d_in[1];
    const int*   sizes     = (const int*)d_in[2];
    const float* emb       = (const float*)d_in[3];
    const float* td_wi = (const float*)d_in[4];
    const float* td_wh = (const float*)d_in[5];
    const float* td_bi = (const float*)d_in[6];
    const float* td_bh = (const float*)d_in[7];
    const float* lg_wi = (const float*)d_in[8];
    const float* lg_wh = (const float*)d_in[9];
    const float* lg_bi = (const float*)d_in[10];
    const float* lg_bh = (const float*)d_in[11];
    const float* ar_wi = (const float*)d_in[12];
    const float* ar_wh = (const float*)d_in[13];
    const float* ar_bi = (const float*)d_in[14];
    const float* ar_bh = (const float*)d_in[15];
    const float* arl_w = (const float*)d_in[16];
    const float* arl_b = (const float*)d_in[17];
    const float* out_w = (const float*)d_in[18];
    const float* out_b = (const float*)d_in[19];
    const float* af_w  = (const float*)d_in[20];
    const float* af_b  = (const float*)d_in[21];
    const float* ad_w  = (const float*)d_in[22];
    const float* ad_b  = (const float*)d_in[23];
    const float* aw_w  = (const float*)d_in[24];
    const float* aw_b  = (const float*)d_in[25];
    float* out = (float*)d_out;

    // ---- workspace carve (floats; every region multiple of 4 floats) ----
    float* ws = (float*)d_ws;
    size_t off = 0;
    auto alloc = [&](size_t n) { float* p = ws + off; off += n; return p; };
    // zero region: 6 f32 states + xtd + xlg + xar (contiguous)
    float* h1   = alloc((size_t)B * D);
    float* c1   = alloc((size_t)B * D);
    float* h2   = alloc((size_t)B * D);
    float* c2   = alloc((size_t)B * D);
    float* arh  = alloc((size_t)B * D);
    float* arc  = alloc((size_t)B * D);
    unsigned short* xtd = (unsigned short*)alloc((size_t)B * 5120 / 2);
    unsigned short* xlg = (unsigned short*)alloc((size_t)B * 4096 / 2);
    unsigned short* xar = (unsigned short*)alloc((size_t)B * 2048 / 2);
    int zero_n = 6 * B * D + (B * 5120 + B * 4096 + B * 2048) / 2;  // 1,507,328
    // rest
    float* prev_h1 = alloc((size_t)B * D);
    float* gates   = alloc((size_t)B * 4096);
    float* h1a     = alloc((size_t)B * A_DIM);
    float* img_att = alloc((size_t)B * NR * A_DIM);
    unsigned short* embs_bf  = (unsigned short*)alloc((size_t)B * TD * E / 2);
    unsigned short* feats_bf = (unsigned short*)alloc((size_t)B * NR * F / 2);
    unsigned short* Wtd  = (unsigned short*)alloc((size_t)4096 * 5120 / 2);
    unsigned short* Wlg  = (unsigned short*)alloc((size_t)4096 * 4096 / 2);
    unsigned short* War  = (unsigned short*)alloc((size_t)4096 * 2048 / 2);
    unsigned short* Wout = (unsigned short*)alloc((size_t)V * 1024 / 2);
    unsigned short* Wad  = (unsigned short*)alloc((size_t)1024 * 1024 / 2);
    unsigned short* Warl = (unsigned short*)alloc((size_t)1024 * 1024 / 2);
    unsigned short* Waf  = (unsigned short*)alloc((size_t)1024 * 2048 / 2);
    int* ip     = (int*)(ws + off);
    int* order  = ip; ip += B;
    int* active = ip; ip += TD + 1;
    int* seqs_s = ip; ip += B * T;

    float* loss_ptr = out + (size_t)B * TD * V + B * T + B;

    // ---- prologue ----
    k_sort_init<<<1, B, 0, stream>>>(sizes, sequences, order, active, seqs_s, out);
    k_zero<<<(zero_n + 255) / 256, 256, 0, stream>>>(h1, zero_n);
    k_favg<<<1024, 256, 0, stream>>>(feats, order, xtd);
    k_emb2bf<<<(B * TD * 128 + 255) / 256, 256, 0, stream>>>(emb, seqs_s, embs_bf);
    k_feats2bf<<<4608, 256, 0, stream>>>(feats, order, feats_bf);
    k_w2bf<<<10240, 256, 0, stream>>>(td_wi, 4096, td_wh, 1024, Wtd, (long)4096 * 640);
    k_w2bf<<<8192, 256, 0, stream>>>(lg_wi, 3072, lg_wh, 1024, Wlg, (long)4096 * 512);
    k_w2bf<<<4096, 256, 0, stream>>>(ar_wi, 1024, ar_wh, 1024, War, (long)4096 * 256);
    k_w2bf<<<5000, 256, 0, stream>>>(out_w, 1024, nullptr, 0, Wout, (long)V * 128);
    k_w2bf<<<512, 256, 0, stream>>>(ad_w, 1024, nullptr, 0, Wad, (long)1024 * 128);
    k_w2bf<<<512, 256, 0, stream>>>(arl_w, 1024, nullptr, 0, Warl, (long)1024 * 128);
    k_w2bf<<<1024, 256, 0, stream>>>(af_w, 2048, nullptr, 0, Waf, (long)1024 * 256);
    // img_att = feats_bf @ Waf^T + af_b   [4608 x 1024]
    k_gemm<<<dim3(32, 36), 256, 0, stream>>>(
        feats_bf, 2048, Waf, 2048, af_b, nullptr,
        img_att, 1024, 1024, 0, nullptr, nullptr, nullptr);

    // ---- timestep loop ----
    for (int t = 0; t < TD; ++t) {
        const int* actp = active + t;
        k_embslot<<<64, 256, 0, stream>>>(embs_bf, xtd, t);
        // top-down LSTM gates
        k_gemm<<<dim3(128, 1), 256, 0, stream>>>(
            xtd, 5120, Wtd, 5120, td_bi, td_bh,
            gates, 4096, 4096, 0, nullptr, nullptr, nullptr);
        k_lstm<<<512, 256, 0, stream>>>(gates, h1, c1, actp, prev_h1,
            xtd + 4096, 5120, xlg + 2048, 4096, xar, 2048);
        // h1 @ ad_w^T + ad_b
        k_gemm<<<dim3(32, 1), 256, 0, stream>>>(
            xlg + 2048, 4096, Wad, 1024, ad_b, nullptr,
            h1a, 1024, 1024, 0, nullptr, nullptr, nullptr);
        k_attn<<<B, 256, 0, stream>>>(h1a, img_att, aw_w, aw_b, feats_bf, xlg);
        // language LSTM gates
        k_gemm<<<dim3(128, 1), 256, 0, stream>>>(
            xlg, 4096, Wlg, 4096, lg_bi, lg_bh,
            gates, 4096, 4096, 0, nullptr, nullptr, nullptr);
        k_lstm<<<512, 256, 0, stream>>>(gates, h2, c2, actp, nullptr,
            xtd, 5120, xlg + 3072, 4096, nullptr, 0);
        // ARNet LSTM gates
        k_gemm<<<dim3(128, 1), 256, 0, stream>>>(
            xar, 2048, War, 2048, ar_bi, ar_bh,
            gates, 4096, 4096, 0, nullptr, nullptr, nullptr);
        k_lstm<<<512, 256, 0, stream>>>(gates, arh, arc, actp, nullptr,
            xar + 1024, 2048, nullptr, 0, nullptr, 0);
        // ARNet loss: (arh @ arl_w^T + arl_b - prev_h1)^2 masked-sum
        if (t > 0)
            k_gemm<<<dim3(32, 1), 256, 0, stream>>>(
                xar + 1024, 2048, Warl, 1024, arl_b, nullptr,
                nullptr, 0, 1024, 1, prev_h1, actp, loss_ptr);
        // preds[:, t, :] = mask * (h2 @ out_w^T + out_b)
        k_gemm<<<dim3((V + 31) / 32, 1), 256, 0, stream>>>(
            xtd, 5120, Wout, 1024, out_b, nullptr,
            out + (size_t)t * V, TD * V, V, 2, nullptr, actp, nullptr);
    }
}